// Round 3
// baseline (167.407 us; speedup 1.0000x reference)
//
#include <hip/hip_runtime.h>
#include <math.h>

// Laplacian-pyramid L1 loss, (2,1,64,256,256), 5 levels, sigma=1 (9-tap), scipy-reflect.
// loss = sum_l mean |lap_pyramid(input - target)[l]|  (linearity of the pyramid).
// 12 launches: k1(0), k2(0), 4x{FATA=[k3(l) || k1(l+1)], FATB=[k4(l) || k2(l+1)]}, k3(4), k4tail.

struct GW { float w[9]; float A, B; };

__device__ __forceinline__ int ridx(int p, int n) {
    // scipy 'reflect' (symmetric) for power-of-two n; valid for p >= -2n
    int m = 2 * n;
    int q = (p + m) & (m - 1);
    return (q < n) ? q : (m - 1 - q);
}

__device__ __forceinline__ void fma4(float4& a, float w, const float4 b) {
    a.x = fmaf(w, b.x, a.x); a.y = fmaf(w, b.y, a.y);
    a.z = fmaf(w, b.z, a.z); a.w = fmaf(w, b.w, a.w);
}

__device__ __forceinline__ float block_sum256(float v) {
    #pragma unroll
    for (int off = 32; off > 0; off >>= 1) v += __shfl_down(v, off, 64);
    __shared__ float wp[4];
    int tid = threadIdx.x;
    if ((tid & 63) == 0) wp[tid >> 6] = v;
    __syncthreads();
    return wp[0] + wp[1] + wp[2] + wp[3];
}

// ---------------------------------------------------------------------------
// k1: fused W+H gaussian on (H,W) slices, emitting only even (y,x) -> (Hd,Wd).
// Tile 64x16 in downsampled space. One slice per call.
template<bool DIFF>
__device__ void dev_k1_slice(const float* __restrict__ inA, const float* __restrict__ inB,
                             float* __restrict__ out,
                             int x0d, int y0d, int slice, int H, int W, int Hd, int Wd, const GW& g)
{
    __shared__ float raw[40][136];
    __shared__ float mid[40][64];
    const size_t in_off  = (size_t)slice * H * W;
    const size_t out_off = (size_t)slice * Hd * Wd;
    const int tid = threadIdx.x;
    const int gy0 = 2*y0d - 4, gx0 = 2*x0d - 4;

    if (2*x0d + 127 < W) {
        // x-interior except 4-col halos: float4 quads for cols 4..131 (16B aligned),
        // scalar reflect for cols 0..3 and 132..135; y reflect resolved per row.
        for (int i = tid; i < 40*32; i += 256) {
            int rr = i >> 5, c4 = (i & 31) + 1;
            int gy = ridx(gy0 + rr, H);
            size_t base = in_off + (size_t)gy * W + gx0 + 4*c4;
            float4 v = *(const float4*)(inA + base);
            if (DIFF) {
                float4 b = *(const float4*)(inB + base);
                v.x -= b.x; v.y -= b.y; v.z -= b.z; v.w -= b.w;
            }
            *(float4*)&raw[rr][4*c4] = v;
        }
        for (int i = tid; i < 40*8; i += 256) {
            int rr = i >> 3, j = i & 7;
            int cc = (j < 4) ? j : (128 + j);
            int gy = ridx(gy0 + rr, H);
            int gx = ridx(gx0 + cc, W);
            size_t idx = in_off + (size_t)gy * W + gx;
            float v = inA[idx];
            if (DIFF) v -= inB[idx];
            raw[rr][cc] = v;
        }
    } else {
        for (int i = tid; i < 40*136; i += 256) {
            int rr = i / 136, cc = i - rr*136;
            int gy = ridx(gy0 + rr, H);
            int gx = ridx(gx0 + cc, W);
            size_t idx = in_off + (size_t)gy * W + gx;
            float v = inA[idx];
            if (DIFF) v -= inB[idx];
            raw[rr][cc] = v;
        }
    }
    __syncthreads();
    for (int i = tid; i < 40*64; i += 256) {
        int rr = i >> 6, c = i & 63;
        float s = 0.f;
        #pragma unroll
        for (int k = 0; k < 9; ++k) s = fmaf(g.w[k], raw[rr][2*c + k], s);
        mid[rr][c] = s;
    }
    __syncthreads();
    {
        int r = tid >> 6, c = tid & 63;
        int ox = x0d + c;
        #pragma unroll
        for (int j = 0; j < 4; ++j) {
            int oy = y0d + r * 4 + j;
            if (oy < Hd && ox < Wd) {
                int rb = 2 * (oy - y0d);
                float s = 0.f;
                #pragma unroll
                for (int k = 0; k < 9; ++k) s = fmaf(g.w[k], mid[rb + k][c], s);
                out[out_off + (size_t)oy * Wd + ox] = s;
            }
        }
    }
}

// ---------------------------------------------------------------------------
// k2: D-axis gaussian + batch(2) reflect mix, at even z -> down. One float4 per elem.
__device__ void dev_k2_elem(long i, const float4* __restrict__ T, float4* __restrict__ O,
                            int D, int Dd, int M4, const GW& g)
{
    if (i >= (long)Dd * M4) return;
    int zd = (int)(i / M4);
    int q  = (int)(i - (long)zd * M4);
    float4 s0 = {0,0,0,0}, s1 = {0,0,0,0};
    if (2*zd - 4 >= 0 && 2*zd + 4 < D) {
        #pragma unroll
        for (int k = 0; k < 9; ++k) {
            int zk = 2*zd - 4 + k;
            fma4(s0, g.w[k], T[(size_t)zk * M4 + q]);
            fma4(s1, g.w[k], T[(size_t)(D + zk) * M4 + q]);
        }
    } else {
        #pragma unroll
        for (int k = 0; k < 9; ++k) {
            int zk = ridx(2*zd - 4 + k, D);
            fma4(s0, g.w[k], T[(size_t)zk * M4 + q]);
            fma4(s1, g.w[k], T[(size_t)(D + zk) * M4 + q]);
        }
    }
    float4 o0, o1;
    o0.x = g.A*s0.x + g.B*s1.x; o0.y = g.A*s0.y + g.B*s1.y;
    o0.z = g.A*s0.z + g.B*s1.z; o0.w = g.A*s0.w + g.B*s1.w;
    o1.x = g.B*s0.x + g.A*s1.x; o1.y = g.B*s0.y + g.A*s1.y;
    o1.z = g.B*s0.z + g.A*s1.z; o1.w = g.B*s0.w + g.A*s1.w;
    O[(size_t)zd * M4 + q] = o0;
    O[(size_t)(Dd + zd) * M4 + q] = o1;
}

// ---------------------------------------------------------------------------
// k3: D-filter of zero-stuffed dn + batch mix (D/batch part of upsample), x8.
__device__ void dev_k3_elem(long i, const float4* __restrict__ Dn, float4* __restrict__ O,
                            int D, int Dd, int M4, const GW& g)
{
    if (i >= (long)D * M4) return;
    int z = (int)(i / M4);
    int q = (int)(i - (long)z * M4);
    float4 s0 = {0,0,0,0}, s1 = {0,0,0,0};
    if (z >= 4 && z + 4 < D) {
        if ((z & 1) == 0) {
            int base = (z >> 1) - 2;
            #pragma unroll
            for (int kk = 0; kk < 5; ++kk) {
                fma4(s0, g.w[2*kk], Dn[(size_t)(base + kk) * M4 + q]);
                fma4(s1, g.w[2*kk], Dn[(size_t)(Dd + base + kk) * M4 + q]);
            }
        } else {
            int base = (z - 3) >> 1;
            #pragma unroll
            for (int kk = 0; kk < 4; ++kk) {
                fma4(s0, g.w[2*kk+1], Dn[(size_t)(base + kk) * M4 + q]);
                fma4(s1, g.w[2*kk+1], Dn[(size_t)(Dd + base + kk) * M4 + q]);
            }
        }
    } else {
        #pragma unroll
        for (int k = 0; k < 9; ++k) {
            int zk = ridx(z - 4 + k, D);
            if ((zk & 1) == 0) {
                int j = zk >> 1;
                fma4(s0, g.w[k], Dn[(size_t)j * M4 + q]);
                fma4(s1, g.w[k], Dn[(size_t)(Dd + j) * M4 + q]);
            }
        }
    }
    float4 o0, o1;
    o0.x = 8.f*(g.A*s0.x + g.B*s1.x); o0.y = 8.f*(g.A*s0.y + g.B*s1.y);
    o0.z = 8.f*(g.A*s0.z + g.B*s1.z); o0.w = 8.f*(g.A*s0.w + g.B*s1.w);
    o1.x = 8.f*(g.B*s0.x + g.A*s1.x); o1.y = 8.f*(g.B*s0.y + g.A*s1.y);
    o1.z = 8.f*(g.B*s0.z + g.A*s1.z); o1.w = 8.f*(g.B*s0.w + g.A*s1.w);
    O[(size_t)z * M4 + q] = o0;
    O[(size_t)(D + z) * M4 + q] = o1;
}

// ---------------------------------------------------------------------------
// k4: up = H-filter(even-row parity) o W-filter of V; returns per-thread sum|cur-up|.
// Tile 64x32 outputs. Leading __syncthreads allows safe reuse in a loop.
template<bool DIFF>
__device__ float dev_k4_slice(const float* __restrict__ V, const float* __restrict__ curA,
                              const float* __restrict__ curB,
                              int x0, int y0, int slice, int H, int W, int Hd, int Wd, const GW& g)
{
    __shared__ float vt[20][72];
    __shared__ float mid[20][64];
    __syncthreads();
    const size_t v_off = (size_t)slice * Hd * Wd;
    const size_t c_off = (size_t)slice * H * W;
    const int tid = threadIdx.x;
    const int vy0 = (y0 >> 1) - 2;
    for (int i = tid; i < 20*72; i += 256) {
        int rr = i / 72, cc = i - rr*72;
        int vy = vy0 + rr;
        int tx = x0 - 4 + cc;
        if (tx < 0) tx = -1 - tx;      // left reflect lands in [0,3] < Wd
        float v = 0.f;
        if (vy >= 0 && vy < Hd && tx < Wd) v = V[v_off + (size_t)vy * Wd + tx];
        vt[rr][cc] = v;                // x >= Wd region of t is zero
    }
    __syncthreads();
    for (int i = tid; i < 20*64; i += 256) {
        int rr = i >> 6, c = i & 63;
        float s = 0.f;
        #pragma unroll
        for (int k = 0; k < 9; ++k) s = fmaf(g.w[k], vt[rr][c + k], s);
        mid[rr][c] = s;
    }
    __syncthreads();
    const bool yin = (y0 >= 4) && (y0 + 35 < H);
    const int c = tid & 63;
    const int ry_base = (tid >> 6) * 8;
    const int ox = x0 + c;
    float lsum = 0.f;
    #pragma unroll
    for (int j = 0; j < 8; ++j) {
        int ry = ry_base + j;
        int oy = y0 + ry;
        if (ox < W && oy < H) {
            float s = 0.f;
            if (yin) {
                if ((j & 1) == 0) {
                    int r0 = ry >> 1;
                    s = g.w[0]*mid[r0][c] + g.w[2]*mid[r0+1][c] + g.w[4]*mid[r0+2][c]
                      + g.w[6]*mid[r0+3][c] + g.w[8]*mid[r0+4][c];
                } else {
                    int r0 = ((ry - 3) >> 1) + 2;
                    s = g.w[1]*mid[r0][c] + g.w[3]*mid[r0+1][c]
                      + g.w[5]*mid[r0+2][c] + g.w[7]*mid[r0+3][c];
                }
            } else {
                #pragma unroll
                for (int k = 0; k < 9; ++k) {
                    int gy = ridx(oy - 4 + k, H);
                    if ((gy & 1) == 0) s = fmaf(g.w[k], mid[(gy >> 1) - vy0][c], s);
                }
            }
            size_t idx = c_off + (size_t)oy * W + ox;
            float cv = curA[idx];
            if (DIFF) cv -= curB[idx];
            lsum += fabsf(cv - s);
        }
    }
    return lsum;
}

// ------------------------------- kernels -----------------------------------
template<bool DIFF>
__global__ __launch_bounds__(256)
void k1_kernel(const float* __restrict__ inA, const float* __restrict__ inB,
               float* __restrict__ out, int H, int W, int Hd, int Wd, GW g)
{
    dev_k1_slice<DIFF>(inA, inB, out, blockIdx.x*64, blockIdx.y*16, blockIdx.z, H, W, Hd, Wd, g);
}

__global__ __launch_bounds__(256)
void k2_kernel(const float* __restrict__ T1, float* __restrict__ dn,
               int D, int Dd, int M4, GW g)
{
    long i = (long)blockIdx.x * 256 + threadIdx.x;
    dev_k2_elem(i, (const float4*)T1, (float4*)dn, D, Dd, M4, g);
}

__global__ __launch_bounds__(256)
void k3_kernel(const float* __restrict__ dn, float* __restrict__ V,
               int D, int Dd, int M4, GW g)
{
    long i = (long)blockIdx.x * 256 + threadIdx.x;
    dev_k3_elem(i, (const float4*)dn, (float4*)V, D, Dd, M4, g);
}

// FATA(l): blocks z<gz1 run k1(l+1) (DIFF=false); the rest flat-index k3(l).
__global__ __launch_bounds__(256)
void kFATA(const float* __restrict__ dn, float* __restrict__ V, int D, int Dd, int M4,
           const float* __restrict__ in1, float* __restrict__ T1,
           int H1, int W1, int Hd1, int Wd1, int gz1, GW g)
{
    if ((int)blockIdx.z < gz1) {
        dev_k1_slice<false>(in1, nullptr, T1, blockIdx.x*64, blockIdx.y*16, blockIdx.z,
                            H1, W1, Hd1, Wd1, g);
    } else {
        long flat = ((long)(blockIdx.z - gz1) * gridDim.y + blockIdx.y) * gridDim.x + blockIdx.x;
        long i = flat * 256 + threadIdx.x;
        dev_k3_elem(i, (const float4*)dn, (float4*)V, D, Dd, M4, g);
    }
}

// FATB(l): blocks z<gz4 run k4(l) (partial per block); the rest flat-index k2(l+1).
template<bool DIFF>
__global__ __launch_bounds__(256)
void kFATB(const float* __restrict__ V, const float* __restrict__ curA,
           const float* __restrict__ curB, float* __restrict__ partials,
           int H, int W, int Hd, int Wd, float inv_numel,
           const float* __restrict__ T1, float* __restrict__ dn2,
           int D2, int Dd2, int M42, int gz4, GW g)
{
    if ((int)blockIdx.z < gz4) {
        float lsum = dev_k4_slice<DIFF>(V, curA, curB, blockIdx.x*64, blockIdx.y*32, blockIdx.z,
                                        H, W, Hd, Wd, g);
        float tot = block_sum256(lsum);
        if (threadIdx.x == 0) {
            int b = blockIdx.x + gridDim.x * (blockIdx.y + gridDim.y * blockIdx.z);
            partials[b] = tot * inv_numel;
        }
    } else {
        long flat = ((long)(blockIdx.z - gz4) * gridDim.y + blockIdx.y) * gridDim.x + blockIdx.x;
        long i = flat * 256 + threadIdx.x;
        dev_k2_elem(i, (const float4*)T1, (float4*)dn2, D2, Dd2, M42, g);
    }
}

// k4tail: single block. Level-4 k4 over all 8 slices + final reduction of partials.
__global__ __launch_bounds__(256)
void k4tail(const float* __restrict__ V, const float* __restrict__ curA,
            const float* __restrict__ P, int np, float* __restrict__ out,
            int H, int W, int Hd, int Wd, float inv_numel, int nslices, GW g)
{
    float lsum = 0.f;
    for (int s = 0; s < nslices; ++s)
        lsum += dev_k4_slice<false>(V, curA, nullptr, 0, 0, s, H, W, Hd, Wd, g);
    lsum *= inv_numel;
    for (int i = threadIdx.x; i < np; i += 256) lsum += P[i];
    float tot = block_sum256(lsum);
    if (threadIdx.x == 0) out[0] = tot;
}

// ---------------------------------------------------------------------------
extern "C" void kernel_launch(void* const* d_in, const int* in_sizes, int n_in,
                              void* d_out, int out_size, void* d_ws, size_t ws_size,
                              hipStream_t stream)
{
    const float* in = (const float*)d_in[0];
    const float* tg = (const float*)d_in[1];
    float* out = (float*)d_out;

    GW g;
    {
        double u[9], S = 0.0;
        for (int k = 0; k < 9; ++k) { double d = k - 4; u[k] = exp(-0.5 * d * d); S += u[k]; }
        for (int k = 0; k < 9; ++k) g.w[k] = (float)(u[k] / S);
        g.A = (float)((2.0*u[0] + u[1] + u[3] + u[4]) / S);  // batch(2) reflect self-weight
        g.B = (float)((u[1] + 2.0*u[2] + u[3]) / S);         // cross-weight
    }

    // level dims
    const int Dl[5]  = {64, 32, 16, 8, 4};
    const int Hl[5]  = {256, 128, 64, 32, 16};
    const int Wl[5]  = {256, 128, 64, 32, 16};
    int Ddl[5], Hdl[5], Wdl[5], M4l[5];
    for (int l = 0; l < 5; ++l) {
        Ddl[l] = Dl[l]/2; Hdl[l] = Hl[l]/2; Wdl[l] = Wl[l]/2;
        M4l[l] = Hdl[l]*Wdl[l]/4;
    }

    // workspace (floats)
    float* T1 = (float*)d_ws;               // 2*64*128*128 = 2097152
    float* V  = T1 + 2*64*128*128;          // 2097152
    float* C1 = V  + 2*64*128*128;
    float* C2 = C1 + 2*32*128*128;
    float* C3 = C2 + 2*16*64*64;
    float* C4 = C3 + 2*8*32*32;
    float* C5 = C4 + 2*4*16*16;
    float* P  = C5 + 2*2*8*8;
    float* C[6] = { nullptr, C1, C2, C3, C4, C5 };

    // partials offsets (k4 block counts per level 0..3)
    int np_off[4], np = 0;
    for (int l = 0; l < 4; ++l) {
        int gx = (Wl[l]+63)/64, gy = (Hl[l]+31)/32;
        np_off[l] = np;
        np += gx * gy * 2 * Dl[l];
    }

    dim3 blk(256);

    // S0: k1(0)
    {
        dim3 gr((Wdl[0]+63)/64, (Hdl[0]+15)/16, 2*Dl[0]);
        k1_kernel<true><<<gr, blk, 0, stream>>>(in, tg, T1, Hl[0], Wl[0], Hdl[0], Wdl[0], g);
    }
    // S1: k2(0) -> C1
    {
        int nb = (int)(((long)Ddl[0]*M4l[0] + 255)/256);
        k2_kernel<<<nb, blk, 0, stream>>>(T1, C[1], Dl[0], Ddl[0], M4l[0], g);
    }
    // main fused ladder
    for (int l = 0; l < 4; ++l) {
        // FATA(l): k3(l) [C[l+1] -> V] || k1(l+1) [C[l+1] -> T1]
        {
            int gx1 = (Wdl[l+1]+63)/64, gy1 = (Hdl[l+1]+15)/16, gz1 = 2*Dl[l+1];
            long n3b = ((long)Dl[l]*M4l[l] + 255)/256;
            long cap = (long)gx1*gy1;
            int lay3 = (int)((n3b + cap - 1)/cap);
            dim3 gr(gx1, gy1, gz1 + lay3);
            kFATA<<<gr, blk, 0, stream>>>(C[l+1], V, Dl[l], Ddl[l], M4l[l],
                                          C[l+1], T1, Hl[l+1], Wl[l+1], Hdl[l+1], Wdl[l+1],
                                          gz1, g);
        }
        // FATB(l): k4(l) [V,cur(l) -> partials] || k2(l+1) [T1 -> C[l+2]]
        {
            int gx4 = (Wl[l]+63)/64, gy4 = (Hl[l]+31)/32, gz4 = 2*Dl[l];
            long n2b = ((long)Ddl[l+1]*M4l[l+1] + 255)/256;
            long cap = (long)gx4*gy4;
            int lay2 = (int)((n2b + cap - 1)/cap);
            dim3 gr(gx4, gy4, gz4 + lay2);
            float invn = 1.0f / ((float)(2*Dl[l]) * Hl[l] * Wl[l]);
            if (l == 0)
                kFATB<true ><<<gr, blk, 0, stream>>>(V, in, tg, P + np_off[0],
                                                     Hl[0], Wl[0], Hdl[0], Wdl[0], invn,
                                                     T1, C[2], Dl[1], Ddl[1], M4l[1], gz4, g);
            else
                kFATB<false><<<gr, blk, 0, stream>>>(V, C[l], nullptr, P + np_off[l],
                                                     Hl[l], Wl[l], Hdl[l], Wdl[l], invn,
                                                     T1, C[l+2], Dl[l+1], Ddl[l+1], M4l[l+1], gz4, g);
        }
    }
    // k3(4): C[5] -> V
    {
        long n3b = ((long)Dl[4]*M4l[4] + 255)/256;
        k3_kernel<<<(unsigned)n3b, blk, 0, stream>>>(C[5], V, Dl[4], Ddl[4], M4l[4], g);
    }
    // k4tail: level-4 k4 (8 slices) + final reduce of P[0..np)
    {
        float invn = 1.0f / ((float)(2*Dl[4]) * Hl[4] * Wl[4]);
        k4tail<<<1, blk, 0, stream>>>(V, C[4], P, np, out,
                                      Hl[4], Wl[4], Hdl[4], Wdl[4], invn, 2*Dl[4], g);
    }
}

// Round 4
// 134.362 us; speedup vs baseline: 1.2459x; 1.2459x over previous
//
#include <hip/hip_runtime.h>
#include <math.h>

// Laplacian-pyramid L1 loss, (2,1,64,256,256), 5 levels, sigma=1 (9-tap), scipy-reflect.
// loss = sum_l mean |lap_pyramid(input - target)[l]|  (linearity of the pyramid).
// 13 launches: k1(0), k2(0), 4x{FATA=[k3(l) || k1(l+1)], FATB=[k4(l) || k2(l+1)]},
//              k3(4), k4(4) parallel, kreduce(1024).

struct GW { float w[9]; float A, B; };

__device__ __forceinline__ int ridx(int p, int n) {
    // scipy 'reflect' (symmetric) for power-of-two n; valid for p >= -2n
    int m = 2 * n;
    int q = (p + m) & (m - 1);
    return (q < n) ? q : (m - 1 - q);
}

__device__ __forceinline__ void fma4(float4& a, float w, const float4 b) {
    a.x = fmaf(w, b.x, a.x); a.y = fmaf(w, b.y, a.y);
    a.z = fmaf(w, b.z, a.z); a.w = fmaf(w, b.w, a.w);
}

__device__ __forceinline__ float block_sum256(float v) {
    #pragma unroll
    for (int off = 32; off > 0; off >>= 1) v += __shfl_down(v, off, 64);
    __shared__ float wp[4];
    int tid = threadIdx.x;
    if ((tid & 63) == 0) wp[tid >> 6] = v;
    __syncthreads();
    return wp[0] + wp[1] + wp[2] + wp[3];
}

// ---------------------------------------------------------------------------
// k1: fused W+H gaussian on (H,W) slices, emitting only even (y,x) -> (Hd,Wd).
// Tile 64x16 in downsampled space. One slice per call.
template<bool DIFF>
__device__ void dev_k1_slice(const float* __restrict__ inA, const float* __restrict__ inB,
                             float* __restrict__ out,
                             int x0d, int y0d, int slice, int H, int W, int Hd, int Wd, const GW& g)
{
    __shared__ float raw[40][136];
    __shared__ float mid[40][64];
    const size_t in_off  = (size_t)slice * H * W;
    const size_t out_off = (size_t)slice * Hd * Wd;
    const int tid = threadIdx.x;
    const int gy0 = 2*y0d - 4, gx0 = 2*x0d - 4;

    if (2*x0d + 127 < W) {
        // float4 quads for cols 4..131 (16B aligned), scalar reflect for 8 halo cols.
        for (int i = tid; i < 40*32; i += 256) {
            int rr = i >> 5, c4 = (i & 31) + 1;
            int gy = ridx(gy0 + rr, H);
            size_t base = in_off + (size_t)gy * W + gx0 + 4*c4;
            float4 v = *(const float4*)(inA + base);
            if (DIFF) {
                float4 b = *(const float4*)(inB + base);
                v.x -= b.x; v.y -= b.y; v.z -= b.z; v.w -= b.w;
            }
            *(float4*)&raw[rr][4*c4] = v;
        }
        for (int i = tid; i < 40*8; i += 256) {
            int rr = i >> 3, j = i & 7;
            int cc = (j < 4) ? j : (128 + j);
            int gy = ridx(gy0 + rr, H);
            int gx = ridx(gx0 + cc, W);
            size_t idx = in_off + (size_t)gy * W + gx;
            float v = inA[idx];
            if (DIFF) v -= inB[idx];
            raw[rr][cc] = v;
        }
    } else {
        for (int i = tid; i < 40*136; i += 256) {
            int rr = i / 136, cc = i - rr*136;
            int gy = ridx(gy0 + rr, H);
            int gx = ridx(gx0 + cc, W);
            size_t idx = in_off + (size_t)gy * W + gx;
            float v = inA[idx];
            if (DIFF) v -= inB[idx];
            raw[rr][cc] = v;
        }
    }
    __syncthreads();
    for (int i = tid; i < 40*64; i += 256) {
        int rr = i >> 6, c = i & 63;
        float s = 0.f;
        #pragma unroll
        for (int k = 0; k < 9; ++k) s = fmaf(g.w[k], raw[rr][2*c + k], s);
        mid[rr][c] = s;
    }
    __syncthreads();
    {
        int r = tid >> 6, c = tid & 63;
        int ox = x0d + c;
        #pragma unroll
        for (int j = 0; j < 4; ++j) {
            int oy = y0d + r * 4 + j;
            if (oy < Hd && ox < Wd) {
                int rb = 2 * (oy - y0d);
                float s = 0.f;
                #pragma unroll
                for (int k = 0; k < 9; ++k) s = fmaf(g.w[k], mid[rb + k][c], s);
                out[out_off + (size_t)oy * Wd + ox] = s;
            }
        }
    }
}

// ---------------------------------------------------------------------------
// k2: D-axis gaussian + batch(2) reflect mix, at even z -> down. One float4 per elem.
__device__ void dev_k2_elem(long i, const float4* __restrict__ T, float4* __restrict__ O,
                            int D, int Dd, int M4, const GW& g)
{
    if (i >= (long)Dd * M4) return;
    int zd = (int)(i / M4);
    int q  = (int)(i - (long)zd * M4);
    float4 s0 = {0,0,0,0}, s1 = {0,0,0,0};
    if (2*zd - 4 >= 0 && 2*zd + 4 < D) {
        #pragma unroll
        for (int k = 0; k < 9; ++k) {
            int zk = 2*zd - 4 + k;
            fma4(s0, g.w[k], T[(size_t)zk * M4 + q]);
            fma4(s1, g.w[k], T[(size_t)(D + zk) * M4 + q]);
        }
    } else {
        #pragma unroll
        for (int k = 0; k < 9; ++k) {
            int zk = ridx(2*zd - 4 + k, D);
            fma4(s0, g.w[k], T[(size_t)zk * M4 + q]);
            fma4(s1, g.w[k], T[(size_t)(D + zk) * M4 + q]);
        }
    }
    float4 o0, o1;
    o0.x = g.A*s0.x + g.B*s1.x; o0.y = g.A*s0.y + g.B*s1.y;
    o0.z = g.A*s0.z + g.B*s1.z; o0.w = g.A*s0.w + g.B*s1.w;
    o1.x = g.B*s0.x + g.A*s1.x; o1.y = g.B*s0.y + g.A*s1.y;
    o1.z = g.B*s0.z + g.A*s1.z; o1.w = g.B*s0.w + g.A*s1.w;
    O[(size_t)zd * M4 + q] = o0;
    O[(size_t)(Dd + zd) * M4 + q] = o1;
}

// ---------------------------------------------------------------------------
// k3: D-filter of zero-stuffed dn + batch mix (D/batch part of upsample), x8.
__device__ void dev_k3_elem(long i, const float4* __restrict__ Dn, float4* __restrict__ O,
                            int D, int Dd, int M4, const GW& g)
{
    if (i >= (long)D * M4) return;
    int z = (int)(i / M4);
    int q = (int)(i - (long)z * M4);
    float4 s0 = {0,0,0,0}, s1 = {0,0,0,0};
    if (z >= 4 && z + 4 < D) {
        if ((z & 1) == 0) {
            int base = (z >> 1) - 2;
            #pragma unroll
            for (int kk = 0; kk < 5; ++kk) {
                fma4(s0, g.w[2*kk], Dn[(size_t)(base + kk) * M4 + q]);
                fma4(s1, g.w[2*kk], Dn[(size_t)(Dd + base + kk) * M4 + q]);
            }
        } else {
            int base = (z - 3) >> 1;
            #pragma unroll
            for (int kk = 0; kk < 4; ++kk) {
                fma4(s0, g.w[2*kk+1], Dn[(size_t)(base + kk) * M4 + q]);
                fma4(s1, g.w[2*kk+1], Dn[(size_t)(Dd + base + kk) * M4 + q]);
            }
        }
    } else {
        #pragma unroll
        for (int k = 0; k < 9; ++k) {
            int zk = ridx(z - 4 + k, D);
            if ((zk & 1) == 0) {
                int j = zk >> 1;
                fma4(s0, g.w[k], Dn[(size_t)j * M4 + q]);
                fma4(s1, g.w[k], Dn[(size_t)(Dd + j) * M4 + q]);
            }
        }
    }
    float4 o0, o1;
    o0.x = 8.f*(g.A*s0.x + g.B*s1.x); o0.y = 8.f*(g.A*s0.y + g.B*s1.y);
    o0.z = 8.f*(g.A*s0.z + g.B*s1.z); o0.w = 8.f*(g.A*s0.w + g.B*s1.w);
    o1.x = 8.f*(g.B*s0.x + g.A*s1.x); o1.y = 8.f*(g.B*s0.y + g.A*s1.y);
    o1.z = 8.f*(g.B*s0.z + g.A*s1.z); o1.w = 8.f*(g.B*s0.w + g.A*s1.w);
    O[(size_t)z * M4 + q] = o0;
    O[(size_t)(D + z) * M4 + q] = o1;
}

// ---------------------------------------------------------------------------
// k4: up = H-filter(even-row parity) o W-filter of V; returns per-thread sum|cur-up|.
// Tile 64x32 outputs.
template<bool DIFF>
__device__ float dev_k4_slice(const float* __restrict__ V, const float* __restrict__ curA,
                              const float* __restrict__ curB,
                              int x0, int y0, int slice, int H, int W, int Hd, int Wd, const GW& g)
{
    __shared__ float vt[20][72];
    __shared__ float mid[20][64];
    const size_t v_off = (size_t)slice * Hd * Wd;
    const size_t c_off = (size_t)slice * H * W;
    const int tid = threadIdx.x;
    const int vy0 = (y0 >> 1) - 2;
    for (int i = tid; i < 20*72; i += 256) {
        int rr = i / 72, cc = i - rr*72;
        int vy = vy0 + rr;
        int tx = x0 - 4 + cc;
        if (tx < 0) tx = -1 - tx;      // left reflect lands in [0,3] < Wd
        float v = 0.f;
        if (vy >= 0 && vy < Hd && tx < Wd) v = V[v_off + (size_t)vy * Wd + tx];
        vt[rr][cc] = v;                // x >= Wd region of t is zero
    }
    __syncthreads();
    for (int i = tid; i < 20*64; i += 256) {
        int rr = i >> 6, c = i & 63;
        float s = 0.f;
        #pragma unroll
        for (int k = 0; k < 9; ++k) s = fmaf(g.w[k], vt[rr][c + k], s);
        mid[rr][c] = s;
    }
    __syncthreads();
    const bool yin = (y0 >= 4) && (y0 + 35 < H);
    const int c = tid & 63;
    const int ry_base = (tid >> 6) * 8;
    const int ox = x0 + c;
    float lsum = 0.f;
    #pragma unroll
    for (int j = 0; j < 8; ++j) {
        int ry = ry_base + j;
        int oy = y0 + ry;
        if (ox < W && oy < H) {
            float s = 0.f;
            if (yin) {
                if ((j & 1) == 0) {
                    int r0 = ry >> 1;
                    s = g.w[0]*mid[r0][c] + g.w[2]*mid[r0+1][c] + g.w[4]*mid[r0+2][c]
                      + g.w[6]*mid[r0+3][c] + g.w[8]*mid[r0+4][c];
                } else {
                    int r0 = ((ry - 3) >> 1) + 2;
                    s = g.w[1]*mid[r0][c] + g.w[3]*mid[r0+1][c]
                      + g.w[5]*mid[r0+2][c] + g.w[7]*mid[r0+3][c];
                }
            } else {
                #pragma unroll
                for (int k = 0; k < 9; ++k) {
                    int gy = ridx(oy - 4 + k, H);
                    if ((gy & 1) == 0) s = fmaf(g.w[k], mid[(gy >> 1) - vy0][c], s);
                }
            }
            size_t idx = c_off + (size_t)oy * W + ox;
            float cv = curA[idx];
            if (DIFF) cv -= curB[idx];
            lsum += fabsf(cv - s);
        }
    }
    return lsum;
}

// ------------------------------- kernels -----------------------------------
template<bool DIFF>
__global__ __launch_bounds__(256)
void k1_kernel(const float* __restrict__ inA, const float* __restrict__ inB,
               float* __restrict__ out, int H, int W, int Hd, int Wd, GW g)
{
    dev_k1_slice<DIFF>(inA, inB, out, blockIdx.x*64, blockIdx.y*16, blockIdx.z, H, W, Hd, Wd, g);
}

__global__ __launch_bounds__(256)
void k2_kernel(const float* __restrict__ T1, float* __restrict__ dn,
               int D, int Dd, int M4, GW g)
{
    long i = (long)blockIdx.x * 256 + threadIdx.x;
    dev_k2_elem(i, (const float4*)T1, (float4*)dn, D, Dd, M4, g);
}

__global__ __launch_bounds__(256)
void k3_kernel(const float* __restrict__ dn, float* __restrict__ V,
               int D, int Dd, int M4, GW g)
{
    long i = (long)blockIdx.x * 256 + threadIdx.x;
    dev_k3_elem(i, (const float4*)dn, (float4*)V, D, Dd, M4, g);
}

template<bool DIFF>
__global__ __launch_bounds__(256)
void k4_kernel(const float* __restrict__ V, const float* __restrict__ curA,
               const float* __restrict__ curB, float* __restrict__ partials,
               int H, int W, int Hd, int Wd, float inv_numel, GW g)
{
    float lsum = dev_k4_slice<DIFF>(V, curA, curB, blockIdx.x*64, blockIdx.y*32, blockIdx.z,
                                    H, W, Hd, Wd, g);
    float tot = block_sum256(lsum);
    if (threadIdx.x == 0) {
        int b = blockIdx.x + gridDim.x * (blockIdx.y + gridDim.y * blockIdx.z);
        partials[b] = tot * inv_numel;
    }
}

// FATA(l): blocks z<gz1 run k1(l+1) (DIFF=false); the rest flat-index k3(l).
__global__ __launch_bounds__(256)
void kFATA(const float* __restrict__ dn, float* __restrict__ V, int D, int Dd, int M4,
           const float* __restrict__ in1, float* __restrict__ T1,
           int H1, int W1, int Hd1, int Wd1, int gz1, GW g)
{
    if ((int)blockIdx.z < gz1) {
        dev_k1_slice<false>(in1, nullptr, T1, blockIdx.x*64, blockIdx.y*16, blockIdx.z,
                            H1, W1, Hd1, Wd1, g);
    } else {
        long flat = ((long)(blockIdx.z - gz1) * gridDim.y + blockIdx.y) * gridDim.x + blockIdx.x;
        long i = flat * 256 + threadIdx.x;
        dev_k3_elem(i, (const float4*)dn, (float4*)V, D, Dd, M4, g);
    }
}

// FATB(l): blocks z<gz4 run k4(l) (partial per block); the rest flat-index k2(l+1).
template<bool DIFF>
__global__ __launch_bounds__(256)
void kFATB(const float* __restrict__ V, const float* __restrict__ curA,
           const float* __restrict__ curB, float* __restrict__ partials,
           int H, int W, int Hd, int Wd, float inv_numel,
           const float* __restrict__ T1, float* __restrict__ dn2,
           int D2, int Dd2, int M42, int gz4, GW g)
{
    if ((int)blockIdx.z < gz4) {
        float lsum = dev_k4_slice<DIFF>(V, curA, curB, blockIdx.x*64, blockIdx.y*32, blockIdx.z,
                                        H, W, Hd, Wd, g);
        float tot = block_sum256(lsum);
        if (threadIdx.x == 0) {
            int b = blockIdx.x + gridDim.x * (blockIdx.y + gridDim.y * blockIdx.z);
            partials[b] = tot * inv_numel;
        }
    } else {
        long flat = ((long)(blockIdx.z - gz4) * gridDim.y + blockIdx.y) * gridDim.x + blockIdx.x;
        long i = flat * 256 + threadIdx.x;
        dev_k2_elem(i, (const float4*)T1, (float4*)dn2, D2, Dd2, M42, g);
    }
}

// kreduce: 1 block x 1024 threads over all partials.
__global__ __launch_bounds__(1024)
void kreduce(const float* __restrict__ P, int n, float* __restrict__ out)
{
    float s = 0.f;
    for (int i = threadIdx.x; i < n; i += 1024) s += P[i];
    #pragma unroll
    for (int off = 32; off > 0; off >>= 1) s += __shfl_down(s, off, 64);
    __shared__ float wp[16];
    if ((threadIdx.x & 63) == 0) wp[threadIdx.x >> 6] = s;
    __syncthreads();
    if (threadIdx.x == 0) {
        float t = 0.f;
        #pragma unroll
        for (int w = 0; w < 16; ++w) t += wp[w];
        out[0] = t;
    }
}

// ---------------------------------------------------------------------------
extern "C" void kernel_launch(void* const* d_in, const int* in_sizes, int n_in,
                              void* d_out, int out_size, void* d_ws, size_t ws_size,
                              hipStream_t stream)
{
    const float* in = (const float*)d_in[0];
    const float* tg = (const float*)d_in[1];
    float* out = (float*)d_out;

    GW g;
    {
        double u[9], S = 0.0;
        for (int k = 0; k < 9; ++k) { double d = k - 4; u[k] = exp(-0.5 * d * d); S += u[k]; }
        for (int k = 0; k < 9; ++k) g.w[k] = (float)(u[k] / S);
        g.A = (float)((2.0*u[0] + u[1] + u[3] + u[4]) / S);  // batch(2) reflect self-weight
        g.B = (float)((u[1] + 2.0*u[2] + u[3]) / S);         // cross-weight
    }

    // level dims
    const int Dl[5]  = {64, 32, 16, 8, 4};
    const int Hl[5]  = {256, 128, 64, 32, 16};
    const int Wl[5]  = {256, 128, 64, 32, 16};
    int Ddl[5], Hdl[5], Wdl[5], M4l[5];
    for (int l = 0; l < 5; ++l) {
        Ddl[l] = Dl[l]/2; Hdl[l] = Hl[l]/2; Wdl[l] = Wl[l]/2;
        M4l[l] = Hdl[l]*Wdl[l]/4;
    }

    // workspace (floats)
    float* T1 = (float*)d_ws;               // 2*64*128*128 = 2097152
    float* V  = T1 + 2*64*128*128;          // 2097152
    float* C1 = V  + 2*64*128*128;
    float* C2 = C1 + 2*32*128*128;
    float* C3 = C2 + 2*16*64*64;
    float* C4 = C3 + 2*8*32*32;
    float* C5 = C4 + 2*4*16*16;
    float* P  = C5 + 2*2*8*8;
    float* C[6] = { nullptr, C1, C2, C3, C4, C5 };

    // partials offsets (k4 block counts per level 0..4)
    int np_off[5], np = 0;
    for (int l = 0; l < 5; ++l) {
        int gx = (Wl[l]+63)/64, gy = (Hl[l]+31)/32;
        np_off[l] = np;
        np += gx * gy * 2 * Dl[l];
    }

    dim3 blk(256);

    // S0: k1(0)
    {
        dim3 gr((Wdl[0]+63)/64, (Hdl[0]+15)/16, 2*Dl[0]);
        k1_kernel<true><<<gr, blk, 0, stream>>>(in, tg, T1, Hl[0], Wl[0], Hdl[0], Wdl[0], g);
    }
    // S1: k2(0) -> C1
    {
        int nb = (int)(((long)Ddl[0]*M4l[0] + 255)/256);
        k2_kernel<<<nb, blk, 0, stream>>>(T1, C[1], Dl[0], Ddl[0], M4l[0], g);
    }
    // main fused ladder
    for (int l = 0; l < 4; ++l) {
        // FATA(l): k3(l) [C[l+1] -> V] || k1(l+1) [C[l+1] -> T1]
        {
            int gx1 = (Wdl[l+1]+63)/64, gy1 = (Hdl[l+1]+15)/16, gz1 = 2*Dl[l+1];
            long n3b = ((long)Dl[l]*M4l[l] + 255)/256;
            long cap = (long)gx1*gy1;
            int lay3 = (int)((n3b + cap - 1)/cap);
            dim3 gr(gx1, gy1, gz1 + lay3);
            kFATA<<<gr, blk, 0, stream>>>(C[l+1], V, Dl[l], Ddl[l], M4l[l],
                                          C[l+1], T1, Hl[l+1], Wl[l+1], Hdl[l+1], Wdl[l+1],
                                          gz1, g);
        }
        // FATB(l): k4(l) [V,cur(l) -> partials] || k2(l+1) [T1 -> C[l+2]]
        {
            int gx4 = (Wl[l]+63)/64, gy4 = (Hl[l]+31)/32, gz4 = 2*Dl[l];
            long n2b = ((long)Ddl[l+1]*M4l[l+1] + 255)/256;
            long cap = (long)gx4*gy4;
            int lay2 = (int)((n2b + cap - 1)/cap);
            dim3 gr(gx4, gy4, gz4 + lay2);
            float invn = 1.0f / ((float)(2*Dl[l]) * Hl[l] * Wl[l]);
            if (l == 0)
                kFATB<true ><<<gr, blk, 0, stream>>>(V, in, tg, P + np_off[0],
                                                     Hl[0], Wl[0], Hdl[0], Wdl[0], invn,
                                                     T1, C[2], Dl[1], Ddl[1], M4l[1], gz4, g);
            else
                kFATB<false><<<gr, blk, 0, stream>>>(V, C[l], nullptr, P + np_off[l],
                                                     Hl[l], Wl[l], Hdl[l], Wdl[l], invn,
                                                     T1, C[l+2], Dl[l+1], Ddl[l+1], M4l[l+1], gz4, g);
        }
    }
    // k3(4): C[5] -> V
    {
        long n3b = ((long)Dl[4]*M4l[4] + 255)/256;
        k3_kernel<<<(unsigned)n3b, blk, 0, stream>>>(C[5], V, Dl[4], Ddl[4], M4l[4], g);
    }
    // k4(4): parallel, 8 blocks -> partials tail
    {
        dim3 gr((Wl[4]+63)/64, (Hl[4]+31)/32, 2*Dl[4]);
        float invn = 1.0f / ((float)(2*Dl[4]) * Hl[4] * Wl[4]);
        k4_kernel<false><<<gr, blk, 0, stream>>>(V, C[4], nullptr, P + np_off[4],
                                                 Hl[4], Wl[4], Hdl[4], Wdl[4], invn, g);
    }
    // final reduce
    kreduce<<<1, 1024, 0, stream>>>(P, np, out);
}